// Round 8
// baseline (38425.961 us; speedup 1.0000x reference)
//
#include <hip/hip_runtime.h>
#include <math.h>

// Problem constants
#define B 128
#define T 1024
#define E 256
#define H 512

// Persistent kernel: 4 replicas x 64 blocks. replica r = bid & 3 owns batch
// rows [32r, 32r+32). Block bu = bid >> 2 owns units [8bu, 8bu+8).
// Compute decomposition: thread (u = tid>>5, kc = tid&31): W for 4 gates x
// unit u x K-chunk [24kc, 24kc+24) in 24 float4 registers (fence-immune).
// Reduce decomposition: thread (u = tid>>5, rr = (tid>>2)&7, q = tid&3).
// Rows processed in 4 groups of 8 per step (xh quarter-tile in LDS).

// ws layout (floats):
//   hbuf  : [2][H][B]  ping-pong h exchange
//   last_h: [H][B]
//   last_c: [H][B]
//   Lsteps: 128 int
//   flags : arrive[4][64] + go[4 x 32-spaced]  (512 ints)
#define HBUF_OFF   0
#define LASTH_OFF  (2*65536)
#define LASTC_OFF  (3*65536)
#define LSTEP_OFF  (4*65536)
#define FLAG_OFF   (4*65536 + 128)

// xh quarter tile: 8 rows x 32 chunks x 26 floats (24 data + 2 pad).
// stride 26 dwords: gcd(26,32)=2 -> 16 banks, 2-way (free). Row stride 834
// (%32==2) so stacked-row staging writes also spread.
#define XROW 834

__device__ __forceinline__ float sigm_f(float x) {
    return 1.f / (1.f + expf(-x));
}
__device__ __forceinline__ void fma4(float4& a, const float4 w, const float4 x) {
    a.x = fmaf(w.x, x.x, a.x);
    a.y = fmaf(w.y, x.y, a.y);
    a.z = fmaf(w.z, x.z, a.z);
    a.w = fmaf(w.w, x.w, a.w);
}

// ---------------------------------------------------------------------------
// init: lengths, h0 -> hbuf[0] ([unit][B]), zero barrier flags
// grid 128 x 256
__global__ __launch_bounds__(256) void init_kernel(
    const int* __restrict__ tokens, const float* __restrict__ h0,
    float* __restrict__ ws) {
    const int b = blockIdx.x, tid = threadIdx.x;
    float* hbuf = ws + HBUF_OFF;
    int* Lsteps = (int*)(ws + LSTEP_OFF);
    int* flags  = (int*)(ws + FLAG_OFF);

    for (int u = tid; u < H; u += 256)
        hbuf[u * B + b] = h0[b * H + u];
    if (b == 0 && tid < 512) flags[tid] = 0;

    __shared__ int s_fz;
    if (tid == 0) s_fz = T;
    __syncthreads();
    int fz = T;
    for (int tt = tid; tt < T; tt += 256)
        if (tokens[b * T + tt] == 0) fz = min(fz, tt);
    atomicMin(&s_fz, fz);
    __syncthreads();
    if (tid == 0) {
        int f = s_fz;
        // steps = first_zero (>=1), or T if no zero / wrap (first_zero==0)
        Lsteps[b] = (f == 0 || f == T) ? T : f;
    }
}

// ---------------------------------------------------------------------------
// persistent LSTM
// grid 256 x 256
__global__ __launch_bounds__(256, 1) void lstm_persist(
    const int* __restrict__ tokens, const float* __restrict__ emb,
    const float* __restrict__ W_ih, const float* __restrict__ b_ih,
    const float* __restrict__ W_hh, const float* __restrict__ b_hh,
    const float* __restrict__ c0,
    float* __restrict__ hbuf, float* __restrict__ last_h,
    float* __restrict__ last_c, const int* __restrict__ Lsteps,
    int* __restrict__ flags) {
    const int tid = threadIdx.x, bid = blockIdx.x;
    const int r  = bid & 3;
    const int bu = bid >> 2;
    const int row0 = r * 32;
    const int u  = tid >> 5;           // unit lane 0..7 (both decompositions)
    const int kc = tid & 31;           // K-chunk lane (compute)
    const int q  = tid & 3;            // kc-quarter (reduce)
    const int rr = (tid >> 2) & 7;     // row-in-group (reduce)
    const int unit = bu * 8 + u;

    int* arrive = flags;               // [4][64]
    int* goflag = flags + 256;         // [4] spaced by 32

    __shared__ float xh[8 * XROW];             // 26.7 KB
    __shared__ float part[8 * 4 * 8 * 33];     // 33.8 KB, [u][g][r][33]
    __shared__ int s_T;

    if (tid == 0) {
        int m = 0;
        for (int i = 0; i < 32; ++i) m = max(m, Lsteps[row0 + i]);
        s_T = m;
    }

    // --- W into registers: 4 gates x 6 float4, cols [24kc, 24kc+24) of 768
    float4 wreg[4][6];
    {
        const int col0 = kc * 24;
#pragma unroll
        for (int g = 0; g < 4; ++g) {
            const int grow = g * H + unit;
#pragma unroll
            for (int j = 0; j < 6; ++j) {
                float v[4];
#pragma unroll
                for (int e = 0; e < 4; ++e) {
                    const int col = col0 + j * 4 + e;
                    v[e] = (col < E) ? W_ih[(size_t)grow * E + col]
                                     : W_hh[(size_t)grow * H + (col - E)];
                }
                wreg[g][j] = make_float4(v[0], v[1], v[2], v[3]);
            }
        }
    }
    float bsum[4];
#pragma unroll
    for (int g = 0; g < 4; ++g)
        bsum[g] = b_ih[g * H + unit] + b_hh[g * H + unit];

    // per-(unit,row) state on q==0 threads: 4 groups
    float creg[4];
    int   Lrow[4];
    if (q == 0) {
#pragma unroll
        for (int gi = 0; gi < 4; ++gi) {
            const int row = row0 + gi * 8 + rr;
            creg[gi] = c0[(size_t)row * H + unit];
            Lrow[gi] = Lsteps[row];
        }
    }
    __syncthreads();
    const int Tg = s_T;

    for (int t = 0; t < Tg; ++t) {
        const float* hprev = hbuf + (t & 1) * (H * B);
        float*       hnext = hbuf + ((t + 1) & 1) * (H * B);

        // ---- load quarter 0 (rows row0..row0+8) into regs ----
        float4 pe[2], ph[4];
        {
            const int prow = row0;
#pragma unroll
            for (int j = 0; j < 2; ++j) {
                const int idx = tid + j * 256;
                const int rl = idx >> 6, c4 = idx & 63;
                const int tok = tokens[(size_t)(prow + rl) * T + t];
                pe[j] = ((const float4*)emb)[(size_t)tok * 64 + c4];
            }
            const float4* hp4 = (const float4*)hprev;
            const int qb = prow >> 2;
#pragma unroll
            for (int j = 0; j < 4; ++j) {
                const int idx = tid + j * 256;
                const int uu = idx >> 1, qq = idx & 1;
                ph[j] = hp4[(size_t)uu * 32 + qb + qq];
            }
        }

#pragma unroll 1
        for (int gi = 0; gi < 4; ++gi) {
            // ---- write quarter gi from regs to LDS ----
#pragma unroll
            for (int j = 0; j < 2; ++j) {
                const int idx = tid + j * 256;
                const int rl = idx >> 6, c4 = idx & 63;
                const int k0 = c4 * 4, c = k0 / 24, rem = k0 % 24;
                float* d = &xh[rl * XROW + c * 26 + rem];
                ((float2*)d)[0] = make_float2(pe[j].x, pe[j].y);
                ((float2*)d)[1] = make_float2(pe[j].z, pe[j].w);
            }
#pragma unroll
            for (int j = 0; j < 4; ++j) {
                const int idx = tid + j * 256;
                const int uu = idx >> 1, qq = idx & 1;
                const int k = 256 + uu, c = k / 24, rem = k % 24;
                const int rb = qq * 4;
                xh[(rb + 0) * XROW + c * 26 + rem] = ph[j].x;
                xh[(rb + 1) * XROW + c * 26 + rem] = ph[j].y;
                xh[(rb + 2) * XROW + c * 26 + rem] = ph[j].z;
                xh[(rb + 3) * XROW + c * 26 + rem] = ph[j].w;
            }
            __syncthreads();

            // ---- prefetch quarter gi+1 (overlaps compute) ----
            if (gi < 3) {
                const int prow = row0 + (gi + 1) * 8;
#pragma unroll
                for (int j = 0; j < 2; ++j) {
                    const int idx = tid + j * 256;
                    const int rl = idx >> 6, c4 = idx & 63;
                    const int tok = tokens[(size_t)(prow + rl) * T + t];
                    pe[j] = ((const float4*)emb)[(size_t)tok * 64 + c4];
                }
                const float4* hp4 = (const float4*)hprev;
                const int qb = prow >> 2;
#pragma unroll
                for (int j = 0; j < 4; ++j) {
                    const int idx = tid + j * 256;
                    const int uu = idx >> 1, qq = idx & 1;
                    ph[j] = hp4[(size_t)uu * 32 + qb + qq];
                }
            }

            // ---- compute 8 rows: 4-gate partial dots over cols [24kc,+24) ----
#pragma unroll 2
            for (int rw = 0; rw < 8; ++rw) {
                const float2* xb2 = (const float2*)&xh[rw * XROW + kc * 26];
                float xr[24];
#pragma unroll
                for (int j = 0; j < 12; ++j) {
                    const float2 v = xb2[j];
                    xr[2 * j] = v.x; xr[2 * j + 1] = v.y;
                }
                float4 a0 = {0,0,0,0}, a1 = {0,0,0,0}, a2 = {0,0,0,0}, a3 = {0,0,0,0};
#pragma unroll
                for (int j = 0; j < 6; ++j) {
                    const float4 x4 = make_float4(xr[4*j], xr[4*j+1], xr[4*j+2], xr[4*j+3]);
                    fma4(a0, wreg[0][j], x4);
                    fma4(a1, wreg[1][j], x4);
                    fma4(a2, wreg[2][j], x4);
                    fma4(a3, wreg[3][j], x4);
                }
                part[((u * 4 + 0) * 8 + rw) * 33 + kc] = a0.x + a0.y + a0.z + a0.w;
                part[((u * 4 + 1) * 8 + rw) * 33 + kc] = a1.x + a1.y + a1.z + a1.w;
                part[((u * 4 + 2) * 8 + rw) * 33 + kc] = a2.x + a2.y + a2.z + a2.w;
                part[((u * 4 + 3) * 8 + rw) * 33 + kc] = a3.x + a3.y + a3.z + a3.w;
            }
            __syncthreads();

            // ---- reduce across kc (8 scalars per gate + 2-stage shuffle) ----
            {
                float s0 = 0.f, s1 = 0.f, s2 = 0.f, s3 = 0.f;
#pragma unroll
                for (int j = 0; j < 8; ++j) {
                    const int kk = q * 8 + j;
                    s0 += part[((u * 4 + 0) * 8 + rr) * 33 + kk];
                    s1 += part[((u * 4 + 1) * 8 + rr) * 33 + kk];
                    s2 += part[((u * 4 + 2) * 8 + rr) * 33 + kk];
                    s3 += part[((u * 4 + 3) * 8 + rr) * 33 + kk];
                }
                s0 += __shfl_xor(s0, 1); s0 += __shfl_xor(s0, 2);
                s1 += __shfl_xor(s1, 1); s1 += __shfl_xor(s1, 2);
                s2 += __shfl_xor(s2, 1); s2 += __shfl_xor(s2, 2);
                s3 += __shfl_xor(s3, 1); s3 += __shfl_xor(s3, 2);
                if (q == 0) {
                    const float ig = sigm_f(s0 + bsum[0]);
                    const float fg = sigm_f(s1 + bsum[1]);
                    const float gv = tanhf(s2 + bsum[2]);
                    const float og = sigm_f(s3 + bsum[3]);
                    const float cn = fg * creg[gi] + ig * gv;
                    const float hn = og * tanhf(cn);
                    creg[gi] = cn;
                    const int row = row0 + gi * 8 + rr;
                    hnext[(size_t)unit * B + row] = hn;
                    if (t == Lrow[gi] - 1) {
                        last_h[(size_t)unit * B + row] = hn;
                        last_c[(size_t)unit * B + row] = cn;
                    }
                }
            }
            __syncthreads();   // part + xh safe to overwrite next group
        }

        // ---- replica barrier: flag array + master broadcast ----
        if (tid == 0)
            __hip_atomic_store(&arrive[r * 64 + bu], t + 1, __ATOMIC_RELEASE,
                               __HIP_MEMORY_SCOPE_AGENT);
        if (bu == 0) {
            if (tid < 64) {
                while (__hip_atomic_load(&arrive[r * 64 + tid], __ATOMIC_RELAXED,
                                         __HIP_MEMORY_SCOPE_AGENT) < t + 1)
                    __builtin_amdgcn_s_sleep(1);
            }
            __syncthreads();
            if (tid == 0) {
                __builtin_amdgcn_fence(__ATOMIC_ACQUIRE, "agent");
                __hip_atomic_store(&goflag[r * 32], t + 1, __ATOMIC_RELEASE,
                                   __HIP_MEMORY_SCOPE_AGENT);
            }
        }
        if (tid == 0) {
            while (__hip_atomic_load(&goflag[r * 32], __ATOMIC_RELAXED,
                                     __HIP_MEMORY_SCOPE_AGENT) < t + 1)
                __builtin_amdgcn_s_sleep(1);
        }
        __syncthreads();
        __builtin_amdgcn_fence(__ATOMIC_ACQUIRE, "agent");
    }
}

// ---------------------------------------------------------------------------
// final: y = [h;c] @ W_proj^T + b_proj ; out = y @ W_out^T + b_out
// grid 128 x 256; last buffers are [unit][B]
__global__ __launch_bounds__(256) void final_kernel(
    const float* __restrict__ last_h, const float* __restrict__ last_c,
    const float* __restrict__ W_proj, const float* __restrict__ b_proj,
    const float* __restrict__ W_out, const float* __restrict__ b_out,
    float* __restrict__ out) {
    const int bg = blockIdx.x, tid = threadIdx.x;

    __shared__ float s_hc[2 * H];
    __shared__ float s_y[H];
    for (int uu = tid; uu < H; uu += 256) {
        s_hc[uu]     = last_h[uu * B + bg];
        s_hc[H + uu] = last_c[uu * B + bg];
    }
    __syncthreads();

    const float4* hc4 = (const float4*)s_hc;
    const float4* Wp4 = (const float4*)W_proj;
#pragma unroll
    for (int jj = 0; jj < 2; ++jj) {
        const int j = tid + jj * 256;
        const float4* wr = Wp4 + (size_t)j * 256;
        float4 acc = {0, 0, 0, 0};
#pragma unroll 4
        for (int kq = 0; kq < 256; ++kq) fma4(acc, wr[kq], hc4[kq]);
        s_y[j] = acc.x + acc.y + acc.z + acc.w + b_proj[j];
    }
    __syncthreads();

    if (tid < 64) {
        float p0 = 0.f, p1 = 0.f;
        for (int j = tid; j < H; j += 64) {
            const float y = s_y[j];
            p0 = fmaf(y, W_out[j], p0);
            p1 = fmaf(y, W_out[H + j], p1);
        }
#pragma unroll
        for (int off = 32; off; off >>= 1) {
            p0 += __shfl_down(p0, off);
            p1 += __shfl_down(p1, off);
        }
        if (tid == 0) {
            out[bg * 2 + 0] = p0 + b_out[0];
            out[bg * 2 + 1] = p1 + b_out[1];
        }
    }
}

// ---------------------------------------------------------------------------
extern "C" void kernel_launch(void* const* d_in, const int* in_sizes, int n_in,
                              void* d_out, int out_size, void* d_ws, size_t ws_size,
                              hipStream_t stream) {
    const int*   tokens = (const int*)d_in[0];
    const float* emb    = (const float*)d_in[1];
    const float* W_ih   = (const float*)d_in[2];
    const float* b_ih   = (const float*)d_in[3];
    const float* W_hh   = (const float*)d_in[4];
    const float* b_hh   = (const float*)d_in[5];
    const float* W_proj = (const float*)d_in[6];
    const float* b_proj = (const float*)d_in[7];
    const float* W_out  = (const float*)d_in[8];
    const float* b_out  = (const float*)d_in[9];
    const float* h0     = (const float*)d_in[10];
    const float* c0     = (const float*)d_in[11];
    float* out = (float*)d_out;
    float* ws  = (float*)d_ws;

    float* hbuf   = ws + HBUF_OFF;
    float* last_h = ws + LASTH_OFF;
    float* last_c = ws + LASTC_OFF;
    int*   Lsteps = (int*)(ws + LSTEP_OFF);
    int*   flags  = (int*)(ws + FLAG_OFF);

    hipLaunchKernelGGL(init_kernel, dim3(B), dim3(256), 0, stream,
                       tokens, h0, ws);

    hipLaunchKernelGGL(lstm_persist, dim3(256), dim3(256), 0, stream,
                       tokens, emb, W_ih, b_ih, W_hh, b_hh, c0,
                       hbuf, last_h, last_c, Lsteps, flags);

    hipLaunchKernelGGL(final_kernel, dim3(B), dim3(256), 0, stream,
                       last_h, last_c, W_proj, b_proj, W_out, b_out, out);
}

// Round 9
// 29272.577 us; speedup vs baseline: 1.3127x; 1.3127x over previous
//
#include <hip/hip_runtime.h>
#include <math.h>

// Problem constants
#define B 128
#define T 1024
#define E 256
#define H 512

// Persistent, FENCE-FREE design (R9):
//  - 8 replicas (g = bid>>5) x 32 blocks (m = bid&31). Replica g owns batch
//    rows [16g,16g+16); block m owns units [16m,16m+16).
//  - h is the ONLY cross-block data. It moves via agent-scope relaxed atomic
//    loads/stores (sc0|sc1: bypass L1/L2, coherent at LLC). Therefore NO
//    acquire/release fences, NO cache invalidation, ever -> W/emb/tokens stay
//    permanently warm in per-XCD L2 (R6's 3.9GB/step refetch eliminated).
//  - 1024 thr/block = 16 waves/CU (R8's 4-wave serialization fixed).
//  - thread = (ul = tid>>6 = wave = unit lane, b = (tid>>2)&15 = row lane,
//    kq = tid&3). 4-gate partial dot over f4 indices k4 = kq+4j; quad
//    __shfl_xor reduce (DPP, no LDS); kq==0 lane owns (unit,row) elementwise
//    state with c in a register for the whole sequence.

// ws layout (floats):
//   hbuf  : [2][H][B]  ping-pong h exchange
//   last_h: [H][B]
//   last_c: [H][B]
//   Lsteps: 128 int
//   flags : arrive[8][32] (int) + go[8 x 32-spaced] (int)  = 512 ints
#define HBUF_OFF   0
#define LASTH_OFF  (2*65536)
#define LASTC_OFF  (3*65536)
#define LSTEP_OFF  (4*65536)
#define FLAG_OFF   (4*65536 + 128)

#define XSTRIDE 772   // xh row stride in floats (768+4: 16B aligned, %32==4)

__device__ __forceinline__ float sigm_f(float x) {
    return 1.f / (1.f + expf(-x));
}
__device__ __forceinline__ void fma4(float4& a, const float4 w, const float4 x) {
    a.x = fmaf(w.x, x.x, a.x);
    a.y = fmaf(w.y, x.y, a.y);
    a.z = fmaf(w.z, x.z, a.z);
    a.w = fmaf(w.w, x.w, a.w);
}

// ---------------------------------------------------------------------------
// init: lengths, h0 -> hbuf[0] ([H][B]), zero barrier flags
// grid 128 x 256
__global__ __launch_bounds__(256) void init_kernel(
    const int* __restrict__ tokens, const float* __restrict__ h0,
    float* __restrict__ ws) {
    const int b = blockIdx.x, tid = threadIdx.x;
    float* hbuf = ws + HBUF_OFF;
    int* Lsteps = (int*)(ws + LSTEP_OFF);
    int* flags  = (int*)(ws + FLAG_OFF);

    for (int u = tid; u < H; u += 256)
        hbuf[u * B + b] = h0[b * H + u];
    if (b == 0)
        for (int i = tid; i < 512; i += 256) flags[i] = 0;

    __shared__ int s_fz;
    if (tid == 0) s_fz = T;
    __syncthreads();
    int fz = T;
    for (int tt = tid; tt < T; tt += 256)
        if (tokens[b * T + tt] == 0) fz = min(fz, tt);
    atomicMin(&s_fz, fz);
    __syncthreads();
    if (tid == 0) {
        int f = s_fz;
        // steps = first_zero (>=1), or T if no zero / wrap (first_zero==0)
        Lsteps[b] = (f == 0 || f == T) ? T : f;
    }
}

// ---------------------------------------------------------------------------
// persistent LSTM
// grid 256 x 1024
__global__ __launch_bounds__(1024) void lstm_persist(
    const int* __restrict__ tokens, const float* __restrict__ emb,
    const float* __restrict__ W_ih, const float* __restrict__ b_ih,
    const float* __restrict__ W_hh, const float* __restrict__ b_hh,
    const float* __restrict__ c0,
    float* __restrict__ hbuf, float* __restrict__ last_h,
    float* __restrict__ last_c, const int* __restrict__ Lsteps,
    int* __restrict__ flags) {
    const int tid = threadIdx.x, bid = blockIdx.x;
    const int g = bid >> 5, m = bid & 31;
    const int row0 = g * 16;
    const int ul = tid >> 6;          // wave / unit lane 0..15
    const int b  = (tid >> 2) & 15;   // row lane
    const int kq = tid & 3;           // K-quad lane
    const int unit = m * 16 + ul;

    int* arrive = flags;              // [8][32]
    int* go     = flags + 256;        // [8], spaced 32 ints

    __shared__ float xh[16 * XSTRIDE];   // 49.4 KB
    __shared__ int s_T;

    if (tid == 0) {
        int mx = 0;
        for (int i = 0; i < 16; ++i) mx = max(mx, Lsteps[row0 + i]);
        s_T = mx;
    }

    // per-(unit,row) elementwise state on kq==0 lanes
    float creg = 0.f, bs0 = 0.f, bs1 = 0.f, bs2 = 0.f, bs3 = 0.f;
    int Lrow = 0;
    if (kq == 0) {
        const int row = row0 + b;
        creg = c0[(size_t)row * H + unit];
        Lrow = Lsteps[row];
        bs0 = b_ih[unit]         + b_hh[unit];
        bs1 = b_ih[H + unit]     + b_hh[H + unit];
        bs2 = b_ih[2 * H + unit] + b_hh[2 * H + unit];
        bs3 = b_ih[3 * H + unit] + b_hh[3 * H + unit];
    }
    __syncthreads();
    const int Tg = s_T;

    const float4* Wi = (const float4*)W_ih;   // rows of 64 f4
    const float4* Wh = (const float4*)W_hh;   // rows of 128 f4
    const size_t xi0 = (size_t)(0 * H + unit) * 64;
    const size_t xi1 = (size_t)(1 * H + unit) * 64;
    const size_t xi2 = (size_t)(2 * H + unit) * 64;
    const size_t xi3 = (size_t)(3 * H + unit) * 64;
    const size_t hi0 = (size_t)(0 * H + unit) * 128;
    const size_t hi1 = (size_t)(1 * H + unit) * 128;
    const size_t hi2 = (size_t)(2 * H + unit) * 128;
    const size_t hi3 = (size_t)(3 * H + unit) * 128;

    for (int t = 0; t < Tg; ++t) {
        const float* hprev = hbuf + (t & 1) * (H * B);
        float*       hnext = hbuf + ((t + 1) & 1) * (H * B);

        // ---- stage x = emb[token]: 16 rows x 64 f4, one per thread ----
        {
            const int rl = tid >> 6, c4 = tid & 63;
            const int tok = tokens[(size_t)(row0 + rl) * T + t];
            ((float4*)&xh[rl * XSTRIDE])[c4] =
                ((const float4*)emb)[(size_t)tok * 64 + c4];
        }
        // ---- stage hprev via LLC-coherent loads (no fences needed) ----
#pragma unroll
        for (int j = 0; j < 8; ++j) {
            const int idx = tid + j * 1024;
            const int u = idx >> 4, bb = idx & 15;
            const float v = __hip_atomic_load(&hprev[u * B + row0 + bb],
                                              __ATOMIC_RELAXED,
                                              __HIP_MEMORY_SCOPE_AGENT);
            xh[bb * XSTRIDE + 256 + u] = v;
        }
        __syncthreads();

        // ---- 4-gate partial dot over k4 = kq + 4j ----
        const float4* xb = (const float4*)&xh[b * XSTRIDE];
        float4 a0 = {0,0,0,0}, a1 = {0,0,0,0}, a2 = {0,0,0,0}, a3 = {0,0,0,0};
#pragma unroll 4
        for (int j = 0; j < 16; ++j) {
            const int k4 = kq + 4 * j;
            const float4 x = xb[k4];
            fma4(a0, Wi[xi0 + k4], x);
            fma4(a1, Wi[xi1 + k4], x);
            fma4(a2, Wi[xi2 + k4], x);
            fma4(a3, Wi[xi3 + k4], x);
        }
#pragma unroll 4
        for (int j = 0; j < 32; ++j) {
            const int k4 = kq + 4 * j;
            const float4 x = xb[64 + k4];
            fma4(a0, Wh[hi0 + k4], x);
            fma4(a1, Wh[hi1 + k4], x);
            fma4(a2, Wh[hi2 + k4], x);
            fma4(a3, Wh[hi3 + k4], x);
        }
        float s0 = a0.x + a0.y + a0.z + a0.w;
        float s1 = a1.x + a1.y + a1.z + a1.w;
        float s2 = a2.x + a2.y + a2.z + a2.w;
        float s3 = a3.x + a3.y + a3.z + a3.w;
        // quad reduce (DPP shuffles, stays off the LDS data path)
        s0 += __shfl_xor(s0, 1); s0 += __shfl_xor(s0, 2);
        s1 += __shfl_xor(s1, 1); s1 += __shfl_xor(s1, 2);
        s2 += __shfl_xor(s2, 1); s2 += __shfl_xor(s2, 2);
        s3 += __shfl_xor(s3, 1); s3 += __shfl_xor(s3, 2);

        if (kq == 0) {
            const float ig = sigm_f(s0 + bs0);
            const float fg = sigm_f(s1 + bs1);
            const float gv = tanhf(s2 + bs2);
            const float og = sigm_f(s3 + bs3);
            const float cn = fg * creg + ig * gv;
            const float hn = og * tanhf(cn);
            creg = cn;
            const int row = row0 + b;
            __hip_atomic_store(&hnext[unit * B + row], hn,
                               __ATOMIC_RELAXED, __HIP_MEMORY_SCOPE_AGENT);
            if (t == Lrow - 1) {
                last_h[(size_t)unit * B + row] = hn;
                last_c[(size_t)unit * B + row] = cn;
            }
        }
        // drain all waves' h-stores (syncthreads waits vmcnt(0) per wave)
        __syncthreads();

        // ---- replica barrier: flag array + master broadcast, NO fences ----
        if (tid == 0)
            __hip_atomic_store(&arrive[g * 32 + m], t + 1, __ATOMIC_RELEASE,
                               __HIP_MEMORY_SCOPE_AGENT);
        if (m == 0) {
            if (tid < 32) {
                while (__hip_atomic_load(&arrive[g * 32 + tid], __ATOMIC_RELAXED,
                                         __HIP_MEMORY_SCOPE_AGENT) < t + 1)
                    __builtin_amdgcn_s_sleep(4);
            }
            __syncthreads();
            if (tid == 0)
                __hip_atomic_store(&go[g * 32], t + 1, __ATOMIC_RELAXED,
                                   __HIP_MEMORY_SCOPE_AGENT);
        } else {
            if (tid == 0) {
                while (__hip_atomic_load(&go[g * 32], __ATOMIC_RELAXED,
                                         __HIP_MEMORY_SCOPE_AGENT) < t + 1)
                    __builtin_amdgcn_s_sleep(4);
            }
        }
        __syncthreads();
        asm volatile("" ::: "memory");   // compiler barrier only
    }
}

// ---------------------------------------------------------------------------
// final: y = [h;c] @ W_proj^T + b_proj ; out = y @ W_out^T + b_out
// grid 128 x 256; last buffers are [H][B]
__global__ __launch_bounds__(256) void final_kernel(
    const float* __restrict__ last_h, const float* __restrict__ last_c,
    const float* __restrict__ W_proj, const float* __restrict__ b_proj,
    const float* __restrict__ W_out, const float* __restrict__ b_out,
    float* __restrict__ out) {
    const int bg = blockIdx.x, tid = threadIdx.x;

    __shared__ float s_hc[2 * H];
    __shared__ float s_y[H];
    for (int uu = tid; uu < H; uu += 256) {
        s_hc[uu]     = last_h[uu * B + bg];
        s_hc[H + uu] = last_c[uu * B + bg];
    }
    __syncthreads();

    const float4* hc4 = (const float4*)s_hc;
    const float4* Wp4 = (const float4*)W_proj;
#pragma unroll
    for (int jj = 0; jj < 2; ++jj) {
        const int j = tid + jj * 256;
        const float4* wr = Wp4 + (size_t)j * 256;
        float4 acc = {0, 0, 0, 0};
#pragma unroll 4
        for (int kq = 0; kq < 256; ++kq) fma4(acc, wr[kq], hc4[kq]);
        s_y[j] = acc.x + acc.y + acc.z + acc.w + b_proj[j];
    }
    __syncthreads();

    if (tid < 64) {
        float p0 = 0.f, p1 = 0.f;
        for (int j = tid; j < H; j += 64) {
            const float y = s_y[j];
            p0 = fmaf(y, W_out[j], p0);
            p1 = fmaf(y, W_out[H + j], p1);
        }
#pragma unroll
        for (int off = 32; off; off >>= 1) {
            p0 += __shfl_down(p0, off);
            p1 += __shfl_down(p1, off);
        }
        if (tid == 0) {
            out[bg * 2 + 0] = p0 + b_out[0];
            out[bg * 2 + 1] = p1 + b_out[1];
        }
    }
}

// ---------------------------------------------------------------------------
extern "C" void kernel_launch(void* const* d_in, const int* in_sizes, int n_in,
                              void* d_out, int out_size, void* d_ws, size_t ws_size,
                              hipStream_t stream) {
    const int*   tokens = (const int*)d_in[0];
    const float* emb    = (const float*)d_in[1];
    const float* W_ih   = (const float*)d_in[2];
    const float* b_ih   = (const float*)d_in[3];
    const float* W_hh   = (const float*)d_in[4];
    const float* b_hh   = (const float*)d_in[5];
    const float* W_proj = (const float*)d_in[6];
    const float* b_proj = (const float*)d_in[7];
    const float* W_out  = (const float*)d_in[8];
    const float* b_out  = (const float*)d_in[9];
    const float* h0     = (const float*)d_in[10];
    const float* c0     = (const float*)d_in[11];
    float* out = (float*)d_out;
    float* ws  = (float*)d_ws;

    float* hbuf   = ws + HBUF_OFF;
    float* last_h = ws + LASTH_OFF;
    float* last_c = ws + LASTC_OFF;
    int*   Lsteps = (int*)(ws + LSTEP_OFF);
    int*   flags  = (int*)(ws + FLAG_OFF);

    hipLaunchKernelGGL(init_kernel, dim3(B), dim3(256), 0, stream,
                       tokens, h0, ws);

    hipLaunchKernelGGL(lstm_persist, dim3(256), dim3(1024), 0, stream,
                       tokens, emb, W_ih, b_ih, W_hh, b_hh, c0,
                       hbuf, last_h, last_c, Lsteps, flags);

    hipLaunchKernelGGL(final_kernel, dim3(B), dim3(256), 0, stream,
                       last_h, last_c, W_proj, b_proj, W_out, b_out, out);
}